// Round 9
// baseline (431.171 us; speedup 1.0000x reference)
//
#include <hip/hip_runtime.h>
#include <hip/hip_bf16.h>

#define BN_RSQ 0.9999950000374997f  // 1/sqrt(1+1e-5)

// ---------------------------------------------------------------------------
// Prefold BN into conv weights: wf = w*g*rsq, bf = b*g*rsq + a.
// Also zeroes the 16-float zero-row buffer used by the direct conv kernels.
// ---------------------------------------------------------------------------
struct LayerP {
  const float* w; const float* b; const float* g; const float* a;
  float* wf; float* bf; int cout; int cin;
};
struct AllP { LayerP L[7]; float* zbuf; };

__global__ void prefold_kernel(AllP A) {
  LayerP p = A.L[blockIdx.y];
  int n = p.cout * p.cin * 9;
  int i = blockIdx.x * 256 + threadIdx.x;
  if (i < n) {
    int o = i / (p.cin * 9);
    p.wf[i] = p.w[i] * p.g[o] * BN_RSQ;
  }
  if (i < p.cout) p.bf[i] = p.b[i] * p.g[i] * BN_RSQ + p.a[i];
  if (blockIdx.y == 0 && blockIdx.x == 0 && i < 16) A.zbuf[i] = 0.f;
}

// Async global->LDS copy: 64 lanes x 4B, LDS dest = wave-uniform base + lane*4.
__device__ __forceinline__ void async_row_f32(const float* g, float* l) {
  __builtin_amdgcn_global_load_lds(
      (const __attribute__((address_space(1))) void*)g,
      (__attribute__((address_space(3))) void*)l, 4, 0, 0);
}

// ---------------------------------------------------------------------------
// Bilinear 2x upsample, align_corners=True (verified r1-r2).
// ---------------------------------------------------------------------------
__global__ void up2_kernel(const float* __restrict__ in, float* __restrict__ out,
                           int Hi, int Wi) {
  const int Ho = 2 * Hi, Wo = 2 * Wi;
  const int ox = blockIdx.x * 16 + threadIdx.x;
  const int oy = blockIdx.y * 16 + threadIdx.y;
  const int bc = blockIdx.z;
  const float sy = (float)(Hi - 1) / (float)(Ho - 1);
  const float sx = (float)(Wi - 1) / (float)(Wo - 1);
  float fy = oy * sy, fx = ox * sx;
  int y0 = (int)floorf(fy); int y1 = min(y0 + 1, Hi - 1);
  int x0 = (int)floorf(fx); int x1 = min(x0 + 1, Wi - 1);
  float wy = fy - (float)y0, wx = fx - (float)x0;
  const float* p = in + (size_t)bc * Hi * Wi;
  float a00 = p[y0 * Wi + x0], a01 = p[y0 * Wi + x1];
  float a10 = p[y1 * Wi + x0], a11 = p[y1 * Wi + x1];
  float r0 = a00 * (1.f - wy) + a10 * wy;
  float r1 = a01 * (1.f - wy) + a11 * wy;
  out[((size_t)bc * Ho + oy) * Wo + ox] = r0 * (1.f - wx) + r1 * wx;
}

// ---------------------------------------------------------------------------
// DIRECT 3x3 conv (+folded BN) + ReLU — no LDS tile, no per-chunk barriers.
//   og-FASTEST z-order (r5 verified): consecutive z-planes share the same
//   batch input -> L2/L3 reuse kills the OSPLIT over-fetch.
//   NOTE: in1/in2 planes must NOT start at the d_ws base (reads p[-1]).
// ---------------------------------------------------------------------------
template <int CIN1, int CIN2, int COUTG, int OSPLIT, bool WRITE_POOL>
__launch_bounds__(256)
__global__ void conv3x3_direct(const float* __restrict__ in1,
                               const float* __restrict__ in2,
                               const float* __restrict__ wf,
                               const float* __restrict__ bf,
                               const float* __restrict__ zbuf,
                               float* __restrict__ out,
                               float* __restrict__ pout, int H, int W) {
  constexpr int CIN = CIN1 + CIN2;
  constexpr int COUT = COUTG * OSPLIT;
  __shared__ float wsm[COUTG * CIN * 12];

  const int tid = threadIdx.x;
  const int txp = (tid & 15) * 4;
  const int ty = tid >> 4;
  const int gx0 = blockIdx.x * 64;
  const int gy0 = blockIdx.y * 16;
  const int og = blockIdx.z % OSPLIT;   // og fastest: adjacent z-planes
  const int b = blockIdx.z / OSPLIT;    // re-read the SAME batch input
  const int obase = og * COUTG;
  const int lane = tid & 63;

  for (int idx = tid; idx < COUTG * CIN * 9; idx += 256) {
    int o = idx / (CIN * 9);
    int r = idx - o * (CIN * 9);
    int c = r / 9;
    int t = r - c * 9;
    wsm[(o * CIN + c) * 12 + t] = wf[((obase + o) * CIN + c) * 9 + t];
  }
  __syncthreads();

  const int ox = gx0 + txp;
  const int oy = gy0 + ty;
  const bool vM = (oy >= 1);
  const bool vP = (oy + 1 < H);
  const float selL = (ox >= 1) ? 1.f : 0.f;
  const float selR = (ox + 4 < W) ? 1.f : 0.f;
  const float* zp = zbuf + 4 - (size_t)ox;  // lane loads land in zbuf[3..8]

  float acc[COUTG][4];
#pragma unroll
  for (int o = 0; o < COUTG; ++o)
#pragma unroll
    for (int i = 0; i < 4; ++i) acc[o][i] = 0.f;

  auto body = [&](const float* __restrict__ plane, int cabs) {
    const float* rC = plane + (size_t)oy * W;
    const float* rM = vM ? (rC - W) : zp;
    const float* rP = vP ? (rC + W) : zp;
    float rr[3][6];
#pragma unroll
    for (int dy = 0; dy < 3; ++dy) {
      const float* p = (dy == 0 ? rM : (dy == 1 ? rC : rP)) + ox;
      float4 v4 = *(const float4*)p;   // 16B aligned (ox % 4 == 0, W % 4 == 0)
      float lm = p[-1];
      float rp = p[4];
      rr[dy][0] = lm * selL;
      rr[dy][1] = v4.x; rr[dy][2] = v4.y; rr[dy][3] = v4.z; rr[dy][4] = v4.w;
      rr[dy][5] = rp * selR;
    }
#pragma unroll
    for (int o = 0; o < COUTG; ++o) {
      const float4* wp = (const float4*)&wsm[(o * CIN + cabs) * 12];
      float4 wa = wp[0];
      float4 wb = wp[1];
      float w8 = wsm[(o * CIN + cabs) * 12 + 8];
#pragma unroll
      for (int i = 0; i < 4; ++i) {
        float s = acc[o][i];
        s = fmaf(rr[0][i + 0], wa.x, s);
        s = fmaf(rr[0][i + 1], wa.y, s);
        s = fmaf(rr[0][i + 2], wa.z, s);
        s = fmaf(rr[1][i + 0], wa.w, s);
        s = fmaf(rr[1][i + 1], wb.x, s);
        s = fmaf(rr[1][i + 2], wb.y, s);
        s = fmaf(rr[2][i + 0], wb.z, s);
        s = fmaf(rr[2][i + 1], wb.w, s);
        s = fmaf(rr[2][i + 2], w8, s);
        acc[o][i] = s;
      }
    }
  };

#pragma unroll 1
  for (int c = 0; c < CIN1; ++c)
    body(in1 + (size_t)(b * CIN1 + c) * H * W, c);
  if (CIN2 > 0) {
#pragma unroll 1
    for (int c = 0; c < CIN2; ++c)
      body(in2 + (size_t)(b * CIN2 + c) * H * W, CIN1 + c);
  }

  const int H2 = H >> 1, W2 = W >> 1;
#pragma unroll
  for (int o = 0; o < COUTG; ++o) {
    float bo = bf[obase + o];
    float rv[4];
#pragma unroll
    for (int i = 0; i < 4; ++i) rv[i] = fmaxf(acc[o][i] + bo, 0.f);
    *(float4*)&out[((size_t)(b * COUT + obase + o) * H + oy) * W + ox] =
        *(float4*)rv;
    if (WRITE_POOL) {
      float m0 = fmaxf(rv[0], rv[1]);
      float m1 = fmaxf(rv[2], rv[3]);
      float q0 = fmaxf(m0, __shfl_down(m0, 16));
      float q1 = fmaxf(m1, __shfl_down(m1, 16));
      if (((lane >> 4) & 1) == 0) {
        float2 pw; pw.x = q0; pw.y = q1;
        *(float2*)&pout[((size_t)(b * COUT + obase + o) * H2 + (oy >> 1)) * W2 +
                        (ox >> 1)] = pw;
      }
    }
  }
}

// ---------------------------------------------------------------------------
// u4 SPECIALIZED v7 = r5 kernel with LATENCY-HIDING REORDER:
//   stage utile (gathers in flight) -> in1 direct conv (register-only, no
//   LDS dep — fills the gather-latency window) -> barrier -> in2 conv.
//   r5/r8 had in1 AFTER the barrier: all waves idled on stage latency.
// ---------------------------------------------------------------------------
__launch_bounds__(256)
__global__ void conv3x3_u4(const float* __restrict__ in1,   // x1 [8,8,512,512]
                           const float* __restrict__ in2,   // uo3 [8,8,256,256]
                           const float* __restrict__ wf,    // [4,16,9]
                           const float* __restrict__ bf,    // [4]
                           const float* __restrict__ wout,  // [4]
                           const float* __restrict__ bout,  // [1]
                           const float* __restrict__ zbuf,
                           float* __restrict__ out) {       // [8,1,512,512]
  constexpr int H = 512, W = 512, Hi = 256, Wi = 256;
  constexpr int CIN1 = 8, CIN2 = 8, CIN = 16, COUT = 4;
  __shared__ float utile[CIN2][18][68];   // upsampled in2: rows gy0-1..gy0+16,
                                          // cols [0]=gx0-1, [1..64], [65]=gx0+64
  __shared__ float4 w4i2[COUT * CIN2][2]; // in2-half weights, taps 0-7
  __shared__ float w8i2[COUT * CIN2];     // in2-half weights, tap 8

  const int tid = threadIdx.x;
  const int lane = tid & 63;
  const int wv = tid >> 6;
  const int txp = (tid & 15) * 4;
  const int ty = tid >> 4;
  const int gx0 = blockIdx.x * 64;
  const int gy0 = blockIdx.y * 16;
  const int b = blockIdx.z;

  // in2-half weight staging: 32 pairs, 1 thread each
  if (tid < COUT * CIN2) {
    const int o = tid >> 3, cc = tid & 7;
    const float* wp = wf + (o * CIN + CIN1 + cc) * 9;
    w4i2[tid][0] = make_float4(wp[0], wp[1], wp[2], wp[3]);
    w4i2[tid][1] = make_float4(wp[4], wp[5], wp[6], wp[7]);
    w8i2[tid] = wp[8];
  }

  // ---- cooperative bilinear staging of in2 (all 4 waves in parallel) ----
  const float sx = (float)(Wi - 1) / (float)(W - 1);
  const float sy = (float)(Hi - 1) / (float)(H - 1);
  const float* in2b = in2 + (size_t)b * CIN2 * Hi * Wi;

  {
    const int gox = gx0 + lane;
    const float fx = gox * sx;
    const int x0 = (int)fx;
    const int x1i = min(x0 + 1, Wi - 1);
    const float wx = fx - (float)x0;
    for (int t5 = wv; t5 < CIN2 * 18; t5 += 4) {   // wave-uniform (c,yy)
      const int c = t5 / 18;
      const int yy = t5 - c * 18;
      const int goy = gy0 + yy - 1;
      float v = 0.f;
      if (goy >= 0 && goy < H) {
        const float fy = goy * sy;
        const int y0 = (int)fy;
        const int y1 = min(y0 + 1, Hi - 1);
        const float wy = fy - (float)y0;
        const float* p0 = in2b + ((size_t)c * Hi + y0) * Wi;
        const float* p1 = in2b + ((size_t)c * Hi + y1) * Wi;
        float a00 = p0[x0], a01 = p0[x1i];
        float a10 = p1[x0], a11 = p1[x1i];
        float r0 = a00 * (1.f - wy) + a10 * wy;
        float r1 = a01 * (1.f - wy) + a11 * wy;
        v = r0 * (1.f - wx) + r1 * wx;
      }
      utile[c][yy][1 + lane] = v;
    }
  }
  // x-halo columns (gox = gx0-1 and gx0+64)
  for (int i = tid; i < 2 * CIN2 * 18; i += 256) {
    const int side = i & 1;
    const int row = i >> 1;
    const int c = row / 18;
    const int yy = row - c * 18;
    const int gox = side ? (gx0 + 64) : (gx0 - 1);
    const int goy = gy0 + yy - 1;
    float v = 0.f;
    if (goy >= 0 && goy < H && gox >= 0 && gox < W) {
      const float fy = goy * sy;
      const float fx = gox * sx;
      const int y0 = (int)fy;
      const int y1 = min(y0 + 1, Hi - 1);
      const int x0 = (int)fx;
      const int x1i = min(x0 + 1, Wi - 1);
      const float wy = fy - (float)y0;
      const float wx = fx - (float)x0;
      const float* p = in2b + (size_t)c * Hi * Wi;
      float a00 = p[y0 * Wi + x0], a01 = p[y0 * Wi + x1i];
      float a10 = p[y1 * Wi + x0], a11 = p[y1 * Wi + x1i];
      float r0 = a00 * (1.f - wy) + a10 * wy;
      float r1 = a01 * (1.f - wy) + a11 * wy;
      v = r0 * (1.f - wx) + r1 * wx;
    }
    utile[c][yy][side ? 65 : 0] = v;
  }

  // ---- conv setup ----
  const int ox = gx0 + txp;
  const int oy = gy0 + ty;
  const bool vM = (oy >= 1);
  const bool vP = (oy + 1 < H);
  const float selL = (ox >= 1) ? 1.f : 0.f;
  const float selR = (ox + 4 < W) ? 1.f : 0.f;
  const float* zp = zbuf + 4 - (size_t)ox;

  float acc[COUT][4];
#pragma unroll
  for (int o = 0; o < COUT; ++o)
#pragma unroll
    for (int i = 0; i < 4; ++i) acc[o][i] = 0.f;

  // in1: direct-from-global, register-only accumulation — runs BEFORE the
  // barrier so its loads/FMAs overlap the staging gathers still in flight.
#pragma unroll 1
  for (int c = 0; c < CIN1; ++c) {
    const float* plane = in1 + (size_t)(b * CIN1 + c) * H * W;
    const float* rC = plane + (size_t)oy * W;
    const float* rM = vM ? (rC - W) : zp;
    const float* rP = vP ? (rC + W) : zp;
    float rr[3][6];
#pragma unroll
    for (int dy = 0; dy < 3; ++dy) {
      const float* p = (dy == 0 ? rM : (dy == 1 ? rC : rP)) + ox;
      float4 v4 = *(const float4*)p;
      float lm = p[-1];
      float rp = p[4];
      rr[dy][0] = lm * selL;
      rr[dy][1] = v4.x; rr[dy][2] = v4.y; rr[dy][3] = v4.z; rr[dy][4] = v4.w;
      rr[dy][5] = rp * selR;
    }
#pragma unroll
    for (int o = 0; o < COUT; ++o) {
      const float* wp = wf + (o * CIN + c) * 9;
      float w0 = wp[0], w1 = wp[1], w2 = wp[2], w3 = wp[3], w4 = wp[4];
      float w5 = wp[5], w6 = wp[6], w7 = wp[7], w8 = wp[8];
#pragma unroll
      for (int i = 0; i < 4; ++i) {
        float s = acc[o][i];
        s = fmaf(rr[0][i + 0], w0, s);
        s = fmaf(rr[0][i + 1], w1, s);
        s = fmaf(rr[0][i + 2], w2, s);
        s = fmaf(rr[1][i + 0], w3, s);
        s = fmaf(rr[1][i + 1], w4, s);
        s = fmaf(rr[1][i + 2], w5, s);
        s = fmaf(rr[2][i + 0], w6, s);
        s = fmaf(rr[2][i + 1], w7, s);
        s = fmaf(rr[2][i + 2], w8, s);
        acc[o][i] = s;
      }
    }
  }

  __syncthreads();   // utile + w4i2 ready; the ONLY barrier

  // in2: from the staged LDS upsample tile; weights from packed LDS
#pragma unroll
  for (int c = 0; c < CIN2; ++c) {
    float rr[3][6];
#pragma unroll
    for (int dy = 0; dy < 3; ++dy) {
      const float* p = &utile[c][ty + dy][txp];
      float4 a4 = *(const float4*)p;       // txp%4==0, stride 272B -> aligned
      float2 b2 = *(const float2*)(p + 4);
      rr[dy][0] = a4.x; rr[dy][1] = a4.y; rr[dy][2] = a4.z; rr[dy][3] = a4.w;
      rr[dy][4] = b2.x; rr[dy][5] = b2.y;
    }
#pragma unroll
    for (int o = 0; o < COUT; ++o) {
      const int pr = o * CIN2 + c;
      float4 wa = w4i2[pr][0];
      float4 wb = w4i2[pr][1];
      float w8 = w8i2[pr];
#pragma unroll
      for (int i = 0; i < 4; ++i) {
        float s = acc[o][i];
        s = fmaf(rr[0][i + 0], wa.x, s);
        s = fmaf(rr[0][i + 1], wa.y, s);
        s = fmaf(rr[0][i + 2], wa.z, s);
        s = fmaf(rr[1][i + 0], wa.w, s);
        s = fmaf(rr[1][i + 1], wb.x, s);
        s = fmaf(rr[1][i + 2], wb.y, s);
        s = fmaf(rr[2][i + 0], wb.z, s);
        s = fmaf(rr[2][i + 1], wb.w, s);
        s = fmaf(rr[2][i + 2], w8, s);
        acc[o][i] = s;
      }
    }
  }

  // fused 1x1 + sigmoid epilogue
  float sv[4];
#pragma unroll
  for (int i = 0; i < 4; ++i) sv[i] = bout[0];
#pragma unroll
  for (int o = 0; o < COUT; ++o) {
    float bo = bf[o], wo = wout[o];
#pragma unroll
    for (int i = 0; i < 4; ++i) {
      float rr2 = fmaxf(acc[o][i] + bo, 0.f);
      sv[i] = fmaf(rr2, wo, sv[i]);
    }
  }
#pragma unroll
  for (int i = 0; i < 4; ++i) sv[i] = 1.f / (1.f + __expf(-sv[i]));
  *(float4*)&out[((size_t)b * H + oy) * W + ox] = *(float4*)sv;
}

// ---------------------------------------------------------------------------
// LDS/async conv — used only by inc (unguarded harness input).
// ---------------------------------------------------------------------------
template <int CIN1, int CIN2, int COUTG, int OSPLIT, bool UP_IN2, bool FUSE_OUT,
          bool WRITE_POOL>
__launch_bounds__(256)
__global__ void conv3x3_cbr(const float* __restrict__ in1,
                            const float* __restrict__ in2,
                            const float* __restrict__ wf,
                            const float* __restrict__ bf,
                            const float* __restrict__ wout,
                            const float* __restrict__ bout,
                            float* __restrict__ out,
                            float* __restrict__ pout, int H, int W) {
  constexpr int CIN = CIN1 + CIN2;
  constexpr int COUT = COUTG * OSPLIT;
  constexpr int PPT = 4;
  constexpr int CHUNK = (CIN < 4) ? CIN : 4;
  constexpr int XS = 68;
  constexpr int YT = 18;
  constexpr int ROWS = CHUNK * YT;

  __shared__ float tile[CHUNK][YT][XS];
  __shared__ float wsm[COUTG * CIN * 12];

  const int tid = threadIdx.x;
  const int txp = (tid & 15) * PPT;
  const int ty = tid >> 4;
  const int gx0 = blockIdx.x * 64;
  const int gy0 = blockIdx.y * 16;
  const int b = blockIdx.z & 7;
  const int og = blockIdx.z >> 3;
  const int obase = og * COUTG;

  const int lane = tid & 63;
  const int wv = tid >> 6;

  const int Hi = H >> 1, Wi = W >> 1;
  const float syf = UP_IN2 ? (float)(Hi - 1) / (float)(H - 1) : 0.f;

  int ux0 = 0, ux1 = 0;
  float uwx = 0.f;
  if (UP_IN2) {
    const float sx = (float)(Wi - 1) / (float)(W - 1);
    float fx = (gx0 + lane) * sx;
    ux0 = (int)fx;
    ux1 = min(ux0 + 1, Wi - 1);
    uwx = fx - (float)ux0;
  }

  for (int idx = tid; idx < COUTG * CIN * 9; idx += 256) {
    int o = idx / (CIN * 9);
    int r = idx - o * (CIN * 9);
    int c = r / 9;
    int t = r - c * 9;
    wsm[(o * CIN + c) * 12 + t] = wf[((obase + o) * CIN + c) * 9 + t];
  }

  float acc[COUTG][PPT];
#pragma unroll
  for (int o = 0; o < COUTG; ++o)
#pragma unroll
    for (int i = 0; i < PPT; ++i) acc[o][i] = 0.f;

  for (int cc = 0; cc < CIN; cc += CHUNK) {
    __syncthreads();
    if (wv < CHUNK) {
      const int c = wv;
      const int cg = cc + c;
      const bool dir1 = (CIN2 == 0 || cg < CIN1);
      if (dir1 || !UP_IN2) {
        const float* src;
        int cb;
        if (dir1) { src = in1; cb = b * CIN1 + cg; }
        else      { src = in2; cb = b * CIN2 + (cg - CIN1); }
        const float* base =
            src + (size_t)cb * H * W + (size_t)(gy0 - 1) * W + gx0 + lane;
#pragma unroll
        for (int yy = 0; yy < YT; ++yy) {
          const int iy = gy0 + yy - 1;
          if (iy >= 0 && iy < H) {
            async_row_f32(base + (size_t)yy * W, &tile[c][yy][1]);
          } else {
            tile[c][yy][1 + lane] = 0.f;
          }
        }
      } else {
        const int cb = b * CIN2 + (cg - CIN1);
#pragma unroll 1
        for (int yy = 0; yy < YT; ++yy) {
          const int iy = gy0 + yy - 1;
          float v = 0.f;
          if (iy >= 0 && iy < H) {
            float fy = iy * syf;
            int y0 = (int)fy;
            int y1 = min(y0 + 1, Hi - 1);
            float wy = fy - (float)y0;
            const float* r0p = in2 + (size_t)(cb * Hi + y0) * Wi;
            const float* r1p = in2 + (size_t)(cb * Hi + y1) * Wi;
            float a00 = r0p[ux0], a01 = r0p[ux1];
            float a10 = r1p[ux0], a11 = r1p[ux1];
            float r0 = a00 * (1.f - wy) + a10 * wy;
            float r1 = a01 * (1.f - wy) + a11 * wy;
            v = r0 * (1.f - uwx) + r1 * uwx;
          }
          tile[c][yy][1 + lane] = v;
        }
      }
    }
    for (int idx = tid; idx < 2 * ROWS; idx += 256) {
      const int row = idx >> 1;
      const int side = idx & 1;
      const int c = row / YT;
      const int yy = row - c * YT;
      const int iy = gy0 + yy - 1;
      const int ix = side ? (gx0 + 64) : (gx0 - 1);
      const int cg = cc + c;
      float v = 0.f;
      if (iy >= 0 && iy < H && ix >= 0 && ix < W) {
        if (CIN2 == 0 || cg < CIN1) {
          const int cb = b * CIN1 + cg;
          v = in1[(size_t)(cb * H + iy) * W + ix];
        } else if (UP_IN2) {
          const int cb = b * CIN2 + (cg - CIN1);
          const float sx = (float)(Wi - 1) / (float)(W - 1);
          float fy = iy * syf, fx = ix * sx;
          int y0 = (int)fy; int y1 = min(y0 + 1, Hi - 1);
          int x0 = (int)fx; int x1 = min(x0 + 1, Wi - 1);
          float wy = fy - (float)y0, wx = fx - (float)x0;
          const float* p = in2 + (size_t)cb * Hi * Wi;
          float a00 = p[y0 * Wi + x0], a01 = p[y0 * Wi + x1];
          float a10 = p[y1 * Wi + x0], a11 = p[y1 * Wi + x1];
          float r0 = a00 * (1.f - wy) + a10 * wy;
          float r1 = a01 * (1.f - wy) + a11 * wy;
          v = r0 * (1.f - wx) + r1 * wx;
        } else {
          const int cb = b * CIN2 + (cg - CIN1);
          v = in2[(size_t)(cb * H + iy) * W + ix];
        }
      }
      tile[c][yy][side ? 65 : 0] = v;
    }
    __syncthreads();
#pragma unroll
    for (int c = 0; c < CHUNK; ++c) {
      float rr[3][6];
#pragma unroll
      for (int dy = 0; dy < 3; ++dy) {
        const float* p = &tile[c][ty + dy][txp];
        float4 a4 = *(const float4*)p;
        float2 b2 = *(const float2*)(p + 4);
        rr[dy][0] = a4.x; rr[dy][1] = a4.y; rr[dy][2] = a4.z; rr[dy][3] = a4.w;
        rr[dy][4] = b2.x; rr[dy][5] = b2.y;
      }
      const int cabs = cc + c;
#pragma unroll
      for (int o = 0; o < COUTG; ++o) {
        const float4* wp = (const float4*)&wsm[(o * CIN + cabs) * 12];
        float4 wa = wp[0];
        float4 wb = wp[1];
        float w8 = wsm[(o * CIN + cabs) * 12 + 8];
#pragma unroll
        for (int i = 0; i < PPT; ++i) {
          float s = acc[o][i];
          s = fmaf(rr[0][i + 0], wa.x, s);
          s = fmaf(rr[0][i + 1], wa.y, s);
          s = fmaf(rr[0][i + 2], wa.z, s);
          s = fmaf(rr[1][i + 0], wa.w, s);
          s = fmaf(rr[1][i + 1], wb.x, s);
          s = fmaf(rr[1][i + 2], wb.y, s);
          s = fmaf(rr[2][i + 0], wb.z, s);
          s = fmaf(rr[2][i + 1], wb.w, s);
          s = fmaf(rr[2][i + 2], w8, s);
          acc[o][i] = s;
        }
      }
    }
  }

  const int oy = gy0 + ty;
  const int ox = gx0 + txp;
  if (FUSE_OUT) {
    float sv[PPT];
#pragma unroll
    for (int i = 0; i < PPT; ++i) sv[i] = bout[0];
#pragma unroll
    for (int o = 0; o < COUTG; ++o) {
      float bo = bf[obase + o], wo = wout[o];
#pragma unroll
      for (int i = 0; i < PPT; ++i) {
        float rr2 = fmaxf(acc[o][i] + bo, 0.f);
        sv[i] = fmaf(rr2, wo, sv[i]);
      }
    }
#pragma unroll
    for (int i = 0; i < PPT; ++i) sv[i] = 1.f / (1.f + __expf(-sv[i]));
    *(float4*)&out[((size_t)b * H + oy) * W + ox] = *(float4*)sv;
  } else {
    const int H2 = H >> 1, W2 = W >> 1;
#pragma unroll
    for (int o = 0; o < COUTG; ++o) {
      float bo = bf[obase + o];
      float rv[PPT];
#pragma unroll
      for (int i = 0; i < PPT; ++i) rv[i] = fmaxf(acc[o][i] + bo, 0.f);
      *(float4*)&out[((size_t)(b * COUT + obase + o) * H + oy) * W + ox] =
          *(float4*)rv;
      if (WRITE_POOL) {
        float m0 = fmaxf(rv[0], rv[1]);
        float m1 = fmaxf(rv[2], rv[3]);
        float q0 = fmaxf(m0, __shfl_down(m0, 16));
        float q1 = fmaxf(m1, __shfl_down(m1, 16));
        if (((lane >> 4) & 1) == 0) {
          float2 pw; pw.x = q0; pw.y = q1;
          *(float2*)&pout[((size_t)(b * COUT + obase + o) * H2 + (oy >> 1)) * W2 +
                          (ox >> 1)] = pw;
        }
      }
    }
  }
}

// ---------------------------------------------------------------------------
// FCAS on the 64x64 channel x4[0,1] — PARALLEL two-phase.
// ---------------------------------------------------------------------------
__global__ void fcas_partial(const float* __restrict__ ch,
                             int* __restrict__ pcnt, int* __restrict__ ncnt) {
  __shared__ float sv[256];
  const int e = blockIdx.x * 256 + threadIdx.x;
  const int s = blockIdx.y;
  sv[threadIdx.x] = ch[s * 256 + threadIdx.x];
  __syncthreads();
  const float v = ch[e];
  int p = 0, n = 0;
#pragma unroll 4
  for (int k = 0; k < 256; ++k) {
    float u = sv[k];
    p += (u > v);
    n += (u == v);
  }
  pcnt[s * 4096 + e] = p;
  ncnt[s * 4096 + e] = n;
}

__global__ void fcas_final(float* __restrict__ ch,
                           const int* __restrict__ pcnt,
                           const int* __restrict__ ncnt,
                           const float* __restrict__ w,
                           const float* __restrict__ bb) {
  const int e = blockIdx.x * 256 + threadIdx.x;
  int p = 0, n = 0;
#pragma unroll
  for (int s = 0; s < 16; ++s) {
    p += pcnt[s * 4096 + e];
    n += ncnt[s * 4096 + e];
  }
  const int el = 4096 - p - n;
  float val = ((float)p * w[0] + bb[0] + (float)n * w[1] + bb[1] +
               (float)el * w[2] + bb[2]) / 3.0f;
  int i = e >> 6, j = e & 63;
  bool interior = (i >= 1) && (i <= 62) && (j >= 1) && (j <= 62);
  if (interior) ch[e] = val;
}

// ---------------------------------------------------------------------------
extern "C" void kernel_launch(void* const* d_in, const int* in_sizes, int n_in,
                              void* d_out, int out_size, void* d_ws, size_t ws_size,
                              hipStream_t stream) {
  const float* x      = (const float*)d_in[0];
  const float* w_inc  = (const float*)d_in[1];
  const float* b_inc  = (const float*)d_in[2];
  const float* g_inc  = (const float*)d_in[3];
  const float* a_inc  = (const float*)d_in[4];
  const float* w_d1   = (const float*)d_in[5];
  const float* b_d1   = (const float*)d_in[6];
  const float* g_d1   = (const float*)d_in[7];
  const float* a_d1   = (const float*)d_in[8];
  const float* w_d2   = (const float*)d_in[9];
  const float* b_d2   = (const float*)d_in[10];
  const float* g_d2   = (const float*)d_in[11];
  const float* a_d2   = (const float*)d_in[12];
  const float* w_d3   = (const float*)d_in[13];
  const float* b_d3   = (const float*)d_in[14];
  const float* g_d3   = (const float*)d_in[15];
  const float* a_d3   = (const float*)d_in[16];
  const float* w_u2   = (const float*)d_in[17];
  const float* b_u2   = (const float*)d_in[18];
  const float* g_u2   = (const float*)d_in[19];
  const float* a_u2   = (const float*)d_in[20];
  const float* w_u3   = (const float*)d_in[21];
  const float* b_u3   = (const float*)d_in[22];
  const float* g_u3   = (const float*)d_in[23];
  const float* a_u3   = (const float*)d_in[24];
  const float* w_u4   = (const float*)d_in[25];
  const float* b_u4   = (const float*)d_in[26];
  const float* g_u4   = (const float*)d_in[27];
  const float* a_u4   = (const float*)d_in[28];
  const float* w_out  = (const float*)d_in[29];
  const float* b_out  = (const float*)d_in[30];
  const float* fcas_w = (const float*)d_in[31];
  const float* fcas_b = (const float*)d_in[32];

  // Workspace layout: SCRATCH FIRST so no conv input plane starts at the
  // d_ws base (the direct-conv edge idiom reads plane[-1], masked by selL).
  float* ws = (float*)d_ws;
  float* zbuf   = ws;                  // 16 floats, 16B-aligned (base)
  float* wf_inc = ws + 16;             // 216
  float* wf_d1  = wf_inc + 216;        // 1152
  float* wf_d2  = wf_d1 + 1152;        // 4608
  float* wf_d3  = wf_d2 + 4608;        // 9216
  float* wf_u2  = wf_d3 + 9216;        // 9216
  float* wf_u3  = wf_u2 + 9216;        // 2304
  float* wf_u4  = wf_u3 + 2304;        // 576
  float* bf_inc = wf_u4 + 576;         // 8
  float* bf_d1  = bf_inc + 8;          // 16
  float* bf_d2  = bf_d1 + 16;          // 32
  float* bf_d3  = bf_d2 + 32;          // 32
  float* bf_u2  = bf_d3 + 32;          // 16
  float* bf_u3  = bf_u2 + 16;          // 8
  float* bf_u4  = bf_u3 + 8;           // 4  (ends at ws+27420)
  int*   pcnt   = (int*)(ws + 27424);  // 16*4096 ints (padded to 16B)
  int*   ncnt   = pcnt + 65536;        // 16*4096 ints
  float* x1  = (float*)(ncnt + 65536); // [8,8,512,512]   16,777,216
  float* p1  = x1 + 16777216;          // [8,8,256,256]    4,194,304
  float* x2  = p1 + 4194304;           // [8,16,256,256]   8,388,608
  float* p2  = x2 + 8388608;           // [8,16,128,128]   2,097,152
  float* x3  = p2 + 2097152;           // [8,32,128,128]   4,194,304
  float* p3  = x3 + 4194304;           // [8,32,64,64]     1,048,576
  float* x4  = p3 + 1048576;           // [8,32,64,64]     1,048,576
  float* upa = x4 + 1048576;           // [8,32,128,128]   4,194,304
  float* uo2 = upa + 4194304;          // [8,16,128,128]   2,097,152
  float* uo3 = uo2 + 2097152;          // [8,8,256,256]    4,194,304
  // upb aliases [x3 ..): x3/p3/x4/upa are dead once u2 finished; uo2 beyond.
  float* upb = x3;                     // [8,16,256,256]   8,388,608 (alias)
  float* outp = (float*)d_out;

  AllP A;
  A.L[0] = {w_inc, b_inc, g_inc, a_inc, wf_inc, bf_inc, 8, 3};
  A.L[1] = {w_d1, b_d1, g_d1, a_d1, wf_d1, bf_d1, 16, 8};
  A.L[2] = {w_d2, b_d2, g_d2, a_d2, wf_d2, bf_d2, 32, 16};
  A.L[3] = {w_d3, b_d3, g_d3, a_d3, wf_d3, bf_d3, 32, 32};
  A.L[4] = {w_u2, b_u2, g_u2, a_u2, wf_u2, bf_u2, 16, 64};
  A.L[5] = {w_u3, b_u3, g_u3, a_u3, wf_u3, bf_u3, 8, 32};
  A.L[6] = {w_u4, b_u4, g_u4, a_u4, wf_u4, bf_u4, 4, 16};
  A.zbuf = zbuf;
  prefold_kernel<<<dim3(36, 7), dim3(256), 0, stream>>>(A);

  dim3 blk(256);
  dim3 blk2(16, 16);

  // inc: 3->8 @512, LDS/async kernel (harness input: no guard bytes), +pool
  conv3x3_cbr<3, 0, 8, 1, false, false, true><<<dim3(8, 32, 8), blk, 0, stream>>>(
      x, nullptr, wf_inc, bf_inc, nullptr, nullptr, x1, p1, 512, 512);
  // d1: p1 -> 8->16 @256, DIRECT, COUTG=4/OS4 (2048 blocks, og-fastest), +pool
  conv3x3_direct<8, 0, 4, 4, true><<<dim3(4, 16, 32), blk, 0, stream>>>(
      p1, nullptr, wf_d1, bf_d1, zbuf, x2, p2, 256, 256);
  // d2: p2 -> 16->32 @128, DIRECT, COUTG=4/OS8 (1024 blocks, og-fastest), +pool
  conv3x3_direct<16, 0, 4, 8, true><<<dim3(2, 8, 64), blk, 0, stream>>>(
      p2, nullptr, wf_d2, bf_d2, zbuf, x3, p3, 128, 128);
  // d3: p3 -> 32->32 @64, DIRECT, COUTG=2/OS16 (512 blocks, og-fastest)
  conv3x3_direct<32, 0, 2, 16, false><<<dim3(1, 4, 128), blk, 0, stream>>>(
      p3, nullptr, wf_d3, bf_d3, zbuf, x4, nullptr, 64, 64);
  // FCAS on x4[0,1]: parallel two-phase (256 + 16 blocks)
  fcas_partial<<<dim3(16, 16), blk, 0, stream>>>(x4 + 4096, pcnt, ncnt);
  fcas_final<<<dim3(16), blk, 0, stream>>>(x4 + 4096, pcnt, ncnt, fcas_w, fcas_b);
  // up2(x4): [8,32,64,64] -> upa [8,32,128,128]
  up2_kernel<<<dim3(8, 8, 256), blk2, 0, stream>>>(x4, upa, 64, 64);
  // u2: cat(x3, upa) 64->16 @128, DIRECT, COUTG=2/OS8 (1024 blocks, og-fastest)
  conv3x3_direct<32, 32, 2, 8, false><<<dim3(2, 8, 64), blk, 0, stream>>>(
      x3, upa, wf_u2, bf_u2, zbuf, uo2, nullptr, 128, 128);
  // up2(uo2): [8,16,128,128] -> upb [8,16,256,256]
  up2_kernel<<<dim3(16, 16, 128), blk2, 0, stream>>>(uo2, upb, 128, 128);
  // u3: cat(x2, upb) 32->8 @256, DIRECT, COUTG=4/OS2 (1024 blocks, og-fastest)
  conv3x3_direct<16, 16, 4, 2, false><<<dim3(4, 16, 16), blk, 0, stream>>>(
      x2, upb, wf_u3, bf_u3, zbuf, uo3, nullptr, 256, 256);
  // u4: v7 — r5 kernel with stage->in1->barrier->in2 latency-hiding reorder
  conv3x3_u4<<<dim3(8, 32, 8), blk, 0, stream>>>(
      x1, uo3, wf_u4, bf_u4, w_out, b_out, zbuf, outp);
}

// Round 10
// 412.633 us; speedup vs baseline: 1.0449x; 1.0449x over previous
//
#include <hip/hip_runtime.h>
#include <hip/hip_bf16.h>

#define BN_RSQ 0.9999950000374997f  // 1/sqrt(1+1e-5)

// ---------------------------------------------------------------------------
// Prefold BN into conv weights: wf = w*g*rsq, bf = b*g*rsq + a.
// Also zeroes the 16-float zero-row buffer used by the direct conv kernels.
// ---------------------------------------------------------------------------
struct LayerP {
  const float* w; const float* b; const float* g; const float* a;
  float* wf; float* bf; int cout; int cin;
};
struct AllP { LayerP L[7]; float* zbuf; };

__global__ void prefold_kernel(AllP A) {
  LayerP p = A.L[blockIdx.y];
  int n = p.cout * p.cin * 9;
  int i = blockIdx.x * 256 + threadIdx.x;
  if (i < n) {
    int o = i / (p.cin * 9);
    p.wf[i] = p.w[i] * p.g[o] * BN_RSQ;
  }
  if (i < p.cout) p.bf[i] = p.b[i] * p.g[i] * BN_RSQ + p.a[i];
  if (blockIdx.y == 0 && blockIdx.x == 0 && i < 16) A.zbuf[i] = 0.f;
}

// Async global->LDS copy: 64 lanes x 4B, LDS dest = wave-uniform base + lane*4.
__device__ __forceinline__ void async_row_f32(const float* g, float* l) {
  __builtin_amdgcn_global_load_lds(
      (const __attribute__((address_space(1))) void*)g,
      (__attribute__((address_space(3))) void*)l, 4, 0, 0);
}

// ---------------------------------------------------------------------------
// Bilinear 2x upsample, align_corners=True (verified r1-r2).
// ---------------------------------------------------------------------------
__global__ void up2_kernel(const float* __restrict__ in, float* __restrict__ out,
                           int Hi, int Wi) {
  const int Ho = 2 * Hi, Wo = 2 * Wi;
  const int ox = blockIdx.x * 16 + threadIdx.x;
  const int oy = blockIdx.y * 16 + threadIdx.y;
  const int bc = blockIdx.z;
  const float sy = (float)(Hi - 1) / (float)(Ho - 1);
  const float sx = (float)(Wi - 1) / (float)(Wo - 1);
  float fy = oy * sy, fx = ox * sx;
  int y0 = (int)floorf(fy); int y1 = min(y0 + 1, Hi - 1);
  int x0 = (int)floorf(fx); int x1 = min(x0 + 1, Wi - 1);
  float wy = fy - (float)y0, wx = fx - (float)x0;
  const float* p = in + (size_t)bc * Hi * Wi;
  float a00 = p[y0 * Wi + x0], a01 = p[y0 * Wi + x1];
  float a10 = p[y1 * Wi + x0], a11 = p[y1 * Wi + x1];
  float r0 = a00 * (1.f - wy) + a10 * wy;
  float r1 = a01 * (1.f - wy) + a11 * wy;
  out[((size_t)bc * Ho + oy) * Wo + ox] = r0 * (1.f - wx) + r1 * wx;
}

// ---------------------------------------------------------------------------
// DIRECT 3x3 conv (+folded BN) + ReLU — no LDS tile, no per-chunk barriers.
//   og-FASTEST z-order (r5 verified): consecutive z-planes share the same
//   batch input -> L2/L3 reuse kills the OSPLIT over-fetch.
//   GUARD=true predicates the two edge loads (p[-1]/p[4]) so the kernel is
//   safe on unguarded harness inputs (r1 crash lesson) — used by inc.
//   GUARD=false inputs must NOT start at the d_ws base (reads p[-1]).
// ---------------------------------------------------------------------------
template <int CIN1, int CIN2, int COUTG, int OSPLIT, bool WRITE_POOL,
          bool GUARD = false>
__launch_bounds__(256)
__global__ void conv3x3_direct(const float* __restrict__ in1,
                               const float* __restrict__ in2,
                               const float* __restrict__ wf,
                               const float* __restrict__ bf,
                               const float* __restrict__ zbuf,
                               float* __restrict__ out,
                               float* __restrict__ pout, int H, int W) {
  constexpr int CIN = CIN1 + CIN2;
  constexpr int COUT = COUTG * OSPLIT;
  __shared__ float wsm[COUTG * CIN * 12];

  const int tid = threadIdx.x;
  const int txp = (tid & 15) * 4;
  const int ty = tid >> 4;
  const int gx0 = blockIdx.x * 64;
  const int gy0 = blockIdx.y * 16;
  const int og = blockIdx.z % OSPLIT;   // og fastest: adjacent z-planes
  const int b = blockIdx.z / OSPLIT;    // re-read the SAME batch input
  const int obase = og * COUTG;
  const int lane = tid & 63;

  for (int idx = tid; idx < COUTG * CIN * 9; idx += 256) {
    int o = idx / (CIN * 9);
    int r = idx - o * (CIN * 9);
    int c = r / 9;
    int t = r - c * 9;
    wsm[(o * CIN + c) * 12 + t] = wf[((obase + o) * CIN + c) * 9 + t];
  }
  __syncthreads();

  const int ox = gx0 + txp;
  const int oy = gy0 + ty;
  const bool vM = (oy >= 1);
  const bool vP = (oy + 1 < H);
  const float selL = (ox >= 1) ? 1.f : 0.f;
  const float selR = (ox + 4 < W) ? 1.f : 0.f;
  const float* zp = zbuf + 4 - (size_t)ox;  // lane loads land in zbuf[3..8]

  float acc[COUTG][4];
#pragma unroll
  for (int o = 0; o < COUTG; ++o)
#pragma unroll
    for (int i = 0; i < 4; ++i) acc[o][i] = 0.f;

  auto body = [&](const float* __restrict__ plane, int cabs) {
    const float* rC = plane + (size_t)oy * W;
    const float* rM = vM ? (rC - W) : zp;
    const float* rP = vP ? (rC + W) : zp;
    float rr[3][6];
#pragma unroll
    for (int dy = 0; dy < 3; ++dy) {
      const float* p = (dy == 0 ? rM : (dy == 1 ? rC : rP)) + ox;
      float4 v4 = *(const float4*)p;   // 16B aligned (ox % 4 == 0, W % 4 == 0)
      float lm, rp;
      if constexpr (GUARD) {
        lm = (selL != 0.f) ? p[-1] : 0.f;   // predicated: address never OOB
        rp = (selR != 0.f) ? p[4] : 0.f;
      } else {
        lm = p[-1] * selL;
        rp = p[4] * selR;
      }
      rr[dy][0] = lm;
      rr[dy][1] = v4.x; rr[dy][2] = v4.y; rr[dy][3] = v4.z; rr[dy][4] = v4.w;
      rr[dy][5] = rp;
    }
#pragma unroll
    for (int o = 0; o < COUTG; ++o) {
      const float4* wp = (const float4*)&wsm[(o * CIN + cabs) * 12];
      float4 wa = wp[0];
      float4 wb = wp[1];
      float w8 = wsm[(o * CIN + cabs) * 12 + 8];
#pragma unroll
      for (int i = 0; i < 4; ++i) {
        float s = acc[o][i];
        s = fmaf(rr[0][i + 0], wa.x, s);
        s = fmaf(rr[0][i + 1], wa.y, s);
        s = fmaf(rr[0][i + 2], wa.z, s);
        s = fmaf(rr[1][i + 0], wa.w, s);
        s = fmaf(rr[1][i + 1], wb.x, s);
        s = fmaf(rr[1][i + 2], wb.y, s);
        s = fmaf(rr[2][i + 0], wb.z, s);
        s = fmaf(rr[2][i + 1], wb.w, s);
        s = fmaf(rr[2][i + 2], w8, s);
        acc[o][i] = s;
      }
    }
  };

#pragma unroll 1
  for (int c = 0; c < CIN1; ++c)
    body(in1 + (size_t)(b * CIN1 + c) * H * W, c);
  if (CIN2 > 0) {
#pragma unroll 1
    for (int c = 0; c < CIN2; ++c)
      body(in2 + (size_t)(b * CIN2 + c) * H * W, CIN1 + c);
  }

  const int H2 = H >> 1, W2 = W >> 1;
#pragma unroll
  for (int o = 0; o < COUTG; ++o) {
    float bo = bf[obase + o];
    float rv[4];
#pragma unroll
    for (int i = 0; i < 4; ++i) rv[i] = fmaxf(acc[o][i] + bo, 0.f);
    *(float4*)&out[((size_t)(b * COUT + obase + o) * H + oy) * W + ox] =
        *(float4*)rv;
    if (WRITE_POOL) {
      float m0 = fmaxf(rv[0], rv[1]);
      float m1 = fmaxf(rv[2], rv[3]);
      float q0 = fmaxf(m0, __shfl_down(m0, 16));
      float q1 = fmaxf(m1, __shfl_down(m1, 16));
      if (((lane >> 4) & 1) == 0) {
        float2 pw; pw.x = q0; pw.y = q1;
        *(float2*)&pout[((size_t)(b * COUT + obase + o) * H2 + (oy >> 1)) * W2 +
                        (ox >> 1)] = pw;
      }
    }
  }
}

// ---------------------------------------------------------------------------
// u4 SPECIALIZED v3 (r5/r8-proven, 74.5us — FINAL): r2 structure + LDS diet.
//   - in2-half weights packed in LDS as float4[32][2]+float[32] (640 B)
//   - in1-half weights read from global with wave-uniform addresses (s_load)
//   r6 (phase-split), r7 (pre-upsample), r9 (reorder) all failed/neutral.
// ---------------------------------------------------------------------------
__launch_bounds__(256)
__global__ void conv3x3_u4(const float* __restrict__ in1,   // x1 [8,8,512,512]
                           const float* __restrict__ in2,   // uo3 [8,8,256,256]
                           const float* __restrict__ wf,    // [4,16,9]
                           const float* __restrict__ bf,    // [4]
                           const float* __restrict__ wout,  // [4]
                           const float* __restrict__ bout,  // [1]
                           const float* __restrict__ zbuf,
                           float* __restrict__ out) {       // [8,1,512,512]
  constexpr int H = 512, W = 512, Hi = 256, Wi = 256;
  constexpr int CIN1 = 8, CIN2 = 8, CIN = 16, COUT = 4;
  __shared__ float utile[CIN2][18][68];   // upsampled in2: rows gy0-1..gy0+16,
                                          // cols [0]=gx0-1, [1..64], [65]=gx0+64
  __shared__ float4 w4i2[COUT * CIN2][2]; // in2-half weights, taps 0-7
  __shared__ float w8i2[COUT * CIN2];     // in2-half weights, tap 8

  const int tid = threadIdx.x;
  const int lane = tid & 63;
  const int wv = tid >> 6;
  const int txp = (tid & 15) * 4;
  const int ty = tid >> 4;
  const int gx0 = blockIdx.x * 64;
  const int gy0 = blockIdx.y * 16;
  const int b = blockIdx.z;

  // in2-half weight staging: 32 pairs, 1 thread each
  if (tid < COUT * CIN2) {
    const int o = tid >> 3, cc = tid & 7;
    const float* wp = wf + (o * CIN + CIN1 + cc) * 9;
    w4i2[tid][0] = make_float4(wp[0], wp[1], wp[2], wp[3]);
    w4i2[tid][1] = make_float4(wp[4], wp[5], wp[6], wp[7]);
    w8i2[tid] = wp[8];
  }

  // ---- cooperative bilinear staging of in2 (all 4 waves in parallel) ----
  const float sx = (float)(Wi - 1) / (float)(W - 1);
  const float sy = (float)(Hi - 1) / (float)(H - 1);
  const float* in2b = in2 + (size_t)b * CIN2 * Hi * Wi;

  {
    const int gox = gx0 + lane;
    const float fx = gox * sx;
    const int x0 = (int)fx;
    const int x1i = min(x0 + 1, Wi - 1);
    const float wx = fx - (float)x0;
    for (int t5 = wv; t5 < CIN2 * 18; t5 += 4) {   // wave-uniform (c,yy)
      const int c = t5 / 18;
      const int yy = t5 - c * 18;
      const int goy = gy0 + yy - 1;
      float v = 0.f;
      if (goy >= 0 && goy < H) {
        const float fy = goy * sy;
        const int y0 = (int)fy;
        const int y1 = min(y0 + 1, Hi - 1);
        const float wy = fy - (float)y0;
        const float* p0 = in2b + ((size_t)c * Hi + y0) * Wi;
        const float* p1 = in2b + ((size_t)c * Hi + y1) * Wi;
        float a00 = p0[x0], a01 = p0[x1i];
        float a10 = p1[x0], a11 = p1[x1i];
        float r0 = a00 * (1.f - wy) + a10 * wy;
        float r1 = a01 * (1.f - wy) + a11 * wy;
        v = r0 * (1.f - wx) + r1 * wx;
      }
      utile[c][yy][1 + lane] = v;
    }
  }
  // x-halo columns (gox = gx0-1 and gx0+64)
  for (int i = tid; i < 2 * CIN2 * 18; i += 256) {
    const int side = i & 1;
    const int row = i >> 1;
    const int c = row / 18;
    const int yy = row - c * 18;
    const int gox = side ? (gx0 + 64) : (gx0 - 1);
    const int goy = gy0 + yy - 1;
    float v = 0.f;
    if (goy >= 0 && goy < H && gox >= 0 && gox < W) {
      const float fy = goy * sy;
      const float fx = gox * sx;
      const int y0 = (int)fy;
      const int y1 = min(y0 + 1, Hi - 1);
      const int x0 = (int)fx;
      const int x1i = min(x0 + 1, Wi - 1);
      const float wy = fy - (float)y0;
      const float wx = fx - (float)x0;
      const float* p = in2b + (size_t)c * Hi * Wi;
      float a00 = p[y0 * Wi + x0], a01 = p[y0 * Wi + x1i];
      float a10 = p[y1 * Wi + x0], a11 = p[y1 * Wi + x1i];
      float r0 = a00 * (1.f - wy) + a10 * wy;
      float r1 = a01 * (1.f - wy) + a11 * wy;
      v = r0 * (1.f - wx) + r1 * wx;
    }
    utile[c][yy][side ? 65 : 0] = v;
  }
  __syncthreads();   // the ONLY barrier

  // ---- conv core ----
  const int ox = gx0 + txp;
  const int oy = gy0 + ty;
  const bool vM = (oy >= 1);
  const bool vP = (oy + 1 < H);
  const float selL = (ox >= 1) ? 1.f : 0.f;
  const float selR = (ox + 4 < W) ? 1.f : 0.f;
  const float* zp = zbuf + 4 - (size_t)ox;

  float acc[COUT][4];
#pragma unroll
  for (int o = 0; o < COUT; ++o)
#pragma unroll
    for (int i = 0; i < 4; ++i) acc[o][i] = 0.f;

  // in1: direct-from-global; weights via wave-uniform addresses (s_load)
#pragma unroll 1
  for (int c = 0; c < CIN1; ++c) {
    const float* plane = in1 + (size_t)(b * CIN1 + c) * H * W;
    const float* rC = plane + (size_t)oy * W;
    const float* rM = vM ? (rC - W) : zp;
    const float* rP = vP ? (rC + W) : zp;
    float rr[3][6];
#pragma unroll
    for (int dy = 0; dy < 3; ++dy) {
      const float* p = (dy == 0 ? rM : (dy == 1 ? rC : rP)) + ox;
      float4 v4 = *(const float4*)p;
      float lm = p[-1];
      float rp = p[4];
      rr[dy][0] = lm * selL;
      rr[dy][1] = v4.x; rr[dy][2] = v4.y; rr[dy][3] = v4.z; rr[dy][4] = v4.w;
      rr[dy][5] = rp * selR;
    }
#pragma unroll
    for (int o = 0; o < COUT; ++o) {
      const float* wp = wf + (o * CIN + c) * 9;
      float w0 = wp[0], w1 = wp[1], w2 = wp[2], w3 = wp[3], w4 = wp[4];
      float w5 = wp[5], w6 = wp[6], w7 = wp[7], w8 = wp[8];
#pragma unroll
      for (int i = 0; i < 4; ++i) {
        float s = acc[o][i];
        s = fmaf(rr[0][i + 0], w0, s);
        s = fmaf(rr[0][i + 1], w1, s);
        s = fmaf(rr[0][i + 2], w2, s);
        s = fmaf(rr[1][i + 0], w3, s);
        s = fmaf(rr[1][i + 1], w4, s);
        s = fmaf(rr[1][i + 2], w5, s);
        s = fmaf(rr[2][i + 0], w6, s);
        s = fmaf(rr[2][i + 1], w7, s);
        s = fmaf(rr[2][i + 2], w8, s);
        acc[o][i] = s;
      }
    }
  }

  // in2: from the staged LDS upsample tile; weights from packed LDS
#pragma unroll
  for (int c = 0; c < CIN2; ++c) {
    float rr[3][6];
#pragma unroll
    for (int dy = 0; dy < 3; ++dy) {
      const float* p = &utile[c][ty + dy][txp];
      float4 a4 = *(const float4*)p;       // txp%4==0, stride 272B -> aligned
      float2 b2 = *(const float2*)(p + 4);
      rr[dy][0] = a4.x; rr[dy][1] = a4.y; rr[dy][2] = a4.z; rr[dy][3] = a4.w;
      rr[dy][4] = b2.x; rr[dy][5] = b2.y;
    }
#pragma unroll
    for (int o = 0; o < COUT; ++o) {
      const int pr = o * CIN2 + c;
      float4 wa = w4i2[pr][0];
      float4 wb = w4i2[pr][1];
      float w8 = w8i2[pr];
#pragma unroll
      for (int i = 0; i < 4; ++i) {
        float s = acc[o][i];
        s = fmaf(rr[0][i + 0], wa.x, s);
        s = fmaf(rr[0][i + 1], wa.y, s);
        s = fmaf(rr[0][i + 2], wa.z, s);
        s = fmaf(rr[1][i + 0], wa.w, s);
        s = fmaf(rr[1][i + 1], wb.x, s);
        s = fmaf(rr[1][i + 2], wb.y, s);
        s = fmaf(rr[2][i + 0], wb.z, s);
        s = fmaf(rr[2][i + 1], wb.w, s);
        s = fmaf(rr[2][i + 2], w8, s);
        acc[o][i] = s;
      }
    }
  }

  // fused 1x1 + sigmoid epilogue
  float sv[4];
#pragma unroll
  for (int i = 0; i < 4; ++i) sv[i] = bout[0];
#pragma unroll
  for (int o = 0; o < COUT; ++o) {
    float bo = bf[o], wo = wout[o];
#pragma unroll
    for (int i = 0; i < 4; ++i) {
      float rr2 = fmaxf(acc[o][i] + bo, 0.f);
      sv[i] = fmaf(rr2, wo, sv[i]);
    }
  }
#pragma unroll
  for (int i = 0; i < 4; ++i) sv[i] = 1.f / (1.f + __expf(-sv[i]));
  *(float4*)&out[((size_t)b * H + oy) * W + ox] = *(float4*)sv;
}

// ---------------------------------------------------------------------------
// FCAS on the 64x64 channel x4[0,1] — PARALLEL two-phase.
// ---------------------------------------------------------------------------
__global__ void fcas_partial(const float* __restrict__ ch,
                             int* __restrict__ pcnt, int* __restrict__ ncnt) {
  __shared__ float sv[256];
  const int e = blockIdx.x * 256 + threadIdx.x;
  const int s = blockIdx.y;
  sv[threadIdx.x] = ch[s * 256 + threadIdx.x];
  __syncthreads();
  const float v = ch[e];
  int p = 0, n = 0;
#pragma unroll 4
  for (int k = 0; k < 256; ++k) {
    float u = sv[k];
    p += (u > v);
    n += (u == v);
  }
  pcnt[s * 4096 + e] = p;
  ncnt[s * 4096 + e] = n;
}

__global__ void fcas_final(float* __restrict__ ch,
                           const int* __restrict__ pcnt,
                           const int* __restrict__ ncnt,
                           const float* __restrict__ w,
                           const float* __restrict__ bb) {
  const int e = blockIdx.x * 256 + threadIdx.x;
  int p = 0, n = 0;
#pragma unroll
  for (int s = 0; s < 16; ++s) {
    p += pcnt[s * 4096 + e];
    n += ncnt[s * 4096 + e];
  }
  const int el = 4096 - p - n;
  float val = ((float)p * w[0] + bb[0] + (float)n * w[1] + bb[1] +
               (float)el * w[2] + bb[2]) / 3.0f;
  int i = e >> 6, j = e & 63;
  bool interior = (i >= 1) && (i <= 62) && (j >= 1) && (j <= 62);
  if (interior) ch[e] = val;
}

// ---------------------------------------------------------------------------
extern "C" void kernel_launch(void* const* d_in, const int* in_sizes, int n_in,
                              void* d_out, int out_size, void* d_ws, size_t ws_size,
                              hipStream_t stream) {
  const float* x      = (const float*)d_in[0];
  const float* w_inc  = (const float*)d_in[1];
  const float* b_inc  = (const float*)d_in[2];
  const float* g_inc  = (const float*)d_in[3];
  const float* a_inc  = (const float*)d_in[4];
  const float* w_d1   = (const float*)d_in[5];
  const float* b_d1   = (const float*)d_in[6];
  const float* g_d1   = (const float*)d_in[7];
  const float* a_d1   = (const float*)d_in[8];
  const float* w_d2   = (const float*)d_in[9];
  const float* b_d2   = (const float*)d_in[10];
  const float* g_d2   = (const float*)d_in[11];
  const float* a_d2   = (const float*)d_in[12];
  const float* w_d3   = (const float*)d_in[13];
  const float* b_d3   = (const float*)d_in[14];
  const float* g_d3   = (const float*)d_in[15];
  const float* a_d3   = (const float*)d_in[16];
  const float* w_u2   = (const float*)d_in[17];
  const float* b_u2   = (const float*)d_in[18];
  const float* g_u2   = (const float*)d_in[19];
  const float* a_u2   = (const float*)d_in[20];
  const float* w_u3   = (const float*)d_in[21];
  const float* b_u3   = (const float*)d_in[22];
  const float* g_u3   = (const float*)d_in[23];
  const float* a_u3   = (const float*)d_in[24];
  const float* w_u4   = (const float*)d_in[25];
  const float* b_u4   = (const float*)d_in[26];
  const float* g_u4   = (const float*)d_in[27];
  const float* a_u4   = (const float*)d_in[28];
  const float* w_out  = (const float*)d_in[29];
  const float* b_out  = (const float*)d_in[30];
  const float* fcas_w = (const float*)d_in[31];
  const float* fcas_b = (const float*)d_in[32];

  // Workspace layout: SCRATCH FIRST so no conv input plane starts at the
  // d_ws base (the direct-conv edge idiom reads plane[-1], masked by selL).
  float* ws = (float*)d_ws;
  float* zbuf   = ws;                  // 16 floats, 16B-aligned (base)
  float* wf_inc = ws + 16;             // 216
  float* wf_d1  = wf_inc + 216;        // 1152
  float* wf_d2  = wf_d1 + 1152;        // 4608
  float* wf_d3  = wf_d2 + 4608;        // 9216
  float* wf_u2  = wf_d3 + 9216;        // 9216
  float* wf_u3  = wf_u2 + 9216;        // 2304
  float* wf_u4  = wf_u3 + 2304;        // 576
  float* bf_inc = wf_u4 + 576;         // 8
  float* bf_d1  = bf_inc + 8;          // 16
  float* bf_d2  = bf_d1 + 16;          // 32
  float* bf_d3  = bf_d2 + 32;          // 32
  float* bf_u2  = bf_d3 + 32;          // 16
  float* bf_u3  = bf_u2 + 16;          // 8
  float* bf_u4  = bf_u3 + 8;           // 4  (ends at ws+27420)
  int*   pcnt   = (int*)(ws + 27424);  // 16*4096 ints (padded to 16B)
  int*   ncnt   = pcnt + 65536;        // 16*4096 ints
  float* x1  = (float*)(ncnt + 65536); // [8,8,512,512]   16,777,216
  float* p1  = x1 + 16777216;          // [8,8,256,256]    4,194,304
  float* x2  = p1 + 4194304;           // [8,16,256,256]   8,388,608
  float* p2  = x2 + 8388608;           // [8,16,128,128]   2,097,152
  float* x3  = p2 + 2097152;           // [8,32,128,128]   4,194,304
  float* p3  = x3 + 4194304;           // [8,32,64,64]     1,048,576
  float* x4  = p3 + 1048576;           // [8,32,64,64]     1,048,576
  float* upa = x4 + 1048576;           // [8,32,128,128]   4,194,304
  float* uo2 = upa + 4194304;          // [8,16,128,128]   2,097,152
  float* uo3 = uo2 + 2097152;          // [8,8,256,256]    4,194,304
  // upb aliases [x3 ..): x3/p3/x4/upa are dead once u2 finished; uo2 beyond.
  float* upb = x3;                     // [8,16,256,256]   8,388,608 (alias)
  float* outp = (float*)d_out;

  AllP A;
  A.L[0] = {w_inc, b_inc, g_inc, a_inc, wf_inc, bf_inc, 8, 3};
  A.L[1] = {w_d1, b_d1, g_d1, a_d1, wf_d1, bf_d1, 16, 8};
  A.L[2] = {w_d2, b_d2, g_d2, a_d2, wf_d2, bf_d2, 32, 16};
  A.L[3] = {w_d3, b_d3, g_d3, a_d3, wf_d3, bf_d3, 32, 32};
  A.L[4] = {w_u2, b_u2, g_u2, a_u2, wf_u2, bf_u2, 16, 64};
  A.L[5] = {w_u3, b_u3, g_u3, a_u3, wf_u3, bf_u3, 8, 32};
  A.L[6] = {w_u4, b_u4, g_u4, a_u4, wf_u4, bf_u4, 4, 16};
  A.zbuf = zbuf;
  prefold_kernel<<<dim3(36, 7), dim3(256), 0, stream>>>(A);

  dim3 blk(256);
  dim3 blk2(16, 16);

  // inc: x -> 3->8 @512, DIRECT with GUARDed edges (harness input), +pool
  conv3x3_direct<3, 0, 8, 1, true, true><<<dim3(8, 32, 8), blk, 0, stream>>>(
      x, nullptr, wf_inc, bf_inc, zbuf, x1, p1, 512, 512);
  // d1: p1 -> 8->16 @256, DIRECT, COUTG=4/OS4 (2048 blocks, og-fastest), +pool
  conv3x3_direct<8, 0, 4, 4, true><<<dim3(4, 16, 32), blk, 0, stream>>>(
      p1, nullptr, wf_d1, bf_d1, zbuf, x2, p2, 256, 256);
  // d2: p2 -> 16->32 @128, DIRECT, COUTG=4/OS8 (1024 blocks, og-fastest), +pool
  conv3x3_direct<16, 0, 4, 8, true><<<dim3(2, 8, 64), blk, 0, stream>>>(
      p2, nullptr, wf_d2, bf_d2, zbuf, x3, p3, 128, 128);
  // d3: p3 -> 32->32 @64, DIRECT, COUTG=2/OS16 (512 blocks, og-fastest)
  conv3x3_direct<32, 0, 2, 16, false><<<dim3(1, 4, 128), blk, 0, stream>>>(
      p3, nullptr, wf_d3, bf_d3, zbuf, x4, nullptr, 64, 64);
  // FCAS on x4[0,1]: parallel two-phase (256 + 16 blocks)
  fcas_partial<<<dim3(16, 16), blk, 0, stream>>>(x4 + 4096, pcnt, ncnt);
  fcas_final<<<dim3(16), blk, 0, stream>>>(x4 + 4096, pcnt, ncnt, fcas_w, fcas_b);
  // up2(x4): [8,32,64,64] -> upa [8,32,128,128]
  up2_kernel<<<dim3(8, 8, 256), blk2, 0, stream>>>(x4, upa, 64, 64);
  // u2: cat(x3, upa) 64->16 @128, DIRECT, COUTG=2/OS8 (1024 blocks, og-fastest)
  conv3x3_direct<32, 32, 2, 8, false><<<dim3(2, 8, 64), blk, 0, stream>>>(
      x3, upa, wf_u2, bf_u2, zbuf, uo2, nullptr, 128, 128);
  // up2(uo2): [8,16,128,128] -> upb [8,16,256,256]
  up2_kernel<<<dim3(16, 16, 128), blk2, 0, stream>>>(uo2, upb, 128, 128);
  // u3: cat(x2, upb) 32->8 @256, DIRECT, COUTG=4/OS2 (1024 blocks, og-fastest)
  conv3x3_direct<16, 16, 4, 2, false><<<dim3(4, 16, 16), blk, 0, stream>>>(
      x2, upb, wf_u3, bf_u3, zbuf, uo3, nullptr, 256, 256);
  // u4: r5/r8-proven staged kernel (39.8 KB LDS, 74.5us, FINAL)
  conv3x3_u4<<<dim3(8, 32, 8), blk, 0, stream>>>(
      x1, uo3, wf_u4, bf_u4, w_out, b_out, zbuf, outp);
}